// Round 9
// baseline (238.821 us; speedup 1.0000x reference)
//
#include <hip/hip_runtime.h>

// Causal depthwise conv1d: out[b,t,f] = sum_k w[k,f] * x[b, t-(K-1)+k, f] + b[f]
// B=4, T=8192, F=1024, K=4. float32.
//
// R1-R6: all cached-access variants pin at 2.3-2.6 TB/s (~86 us kernel).
// R8 (nt loads + nt stores): kernel ~70-72 us — dropped below the 79 us fills.
//   => cache interaction was real. But nt loads forfeit the ~50% read hit rate
//   the harness's restore-copy leaves in L2/L3 (FETCH was 66-78 MB vs 134 MB
//   input in R1-R6).
// R9: cached loads (keep the free hits + cache-absorbed halo) + NT STORES
//   (keep the output stream out of the caches). Single variable vs R8.

typedef float v4f __attribute__((ext_vector_type(4)));

constexpr int Tc = 8192;
constexpr int Fc = 1024;
constexpr int TCHUNK = 16;                 // t-rows per block
constexpr int CHUNKS = Tc / TCHUNK;        // 512
constexpr int NBLK = 4 * CHUNKS;           // 2048 blocks (B=4)

__global__ __launch_bounds__(256) void causal_conv1d_kernel(
    const float* __restrict__ x,
    const float* __restrict__ w,      // (K,1,F) -> w[k*F + f]
    const float* __restrict__ bias,   // (F,)
    float* __restrict__ out)
{
    const int f   = threadIdx.x * 4;  // feature group of 4
    const int bt  = blockIdx.x;
    const int b   = bt / CHUNKS;
    const int t0  = (bt % CHUNKS) * TCHUNK;

    const v4f w0 = *reinterpret_cast<const v4f*>(w + 0 * Fc + f);
    const v4f w1 = *reinterpret_cast<const v4f*>(w + 1 * Fc + f);
    const v4f w2 = *reinterpret_cast<const v4f*>(w + 2 * Fc + f);
    const v4f w3 = *reinterpret_cast<const v4f*>(w + 3 * Fc + f);
    const v4f bv = *reinterpret_cast<const v4f*>(bias + f);

    const float* xp = x   + (size_t)b * Tc * Fc + f;
    float*       op = out + (size_t)b * Tc * Fc + f;

    // Window rows t0-3..t0-1 (halo; cached — L2/L3-absorbed)
    v4f xm3, xm2, xm1;
    if (t0 >= 3) {
        xm3 = *reinterpret_cast<const v4f*>(xp + (size_t)(t0 - 3) * Fc);
        xm2 = *reinterpret_cast<const v4f*>(xp + (size_t)(t0 - 2) * Fc);
        xm1 = *reinterpret_cast<const v4f*>(xp + (size_t)(t0 - 1) * Fc);
    } else {
        xm3 = (v4f)(0.f);
        xm2 = (v4f)(0.f);
        xm1 = (v4f)(0.f);
    }

    // ---------- phase 1: issue all TCHUNK independent cached loads ----------
    v4f xc[TCHUNK];
#pragma unroll
    for (int i = 0; i < TCHUNK; ++i) {
        xc[i] = *reinterpret_cast<const v4f*>(xp + (size_t)(t0 + i) * Fc);
    }

    // Fence: loads may not be sunk past this point.
    __builtin_amdgcn_sched_barrier(0);

    // ---------- phase 2: compute + nt store ----------
#pragma unroll
    for (int i = 0; i < TCHUNK; ++i) {
        v4f o = w3 * xc[i] + w2 * xm1 + w1 * xm2 + w0 * xm3 + bv;
        __builtin_nontemporal_store(o,
            reinterpret_cast<v4f*>(op + (size_t)(t0 + i) * Fc));
        xm3 = xm2; xm2 = xm1; xm1 = xc[i];
    }
}

extern "C" void kernel_launch(void* const* d_in, const int* in_sizes, int n_in,
                              void* d_out, int out_size, void* d_ws, size_t ws_size,
                              hipStream_t stream) {
    const float* x    = (const float*)d_in[0];
    const float* w    = (const float*)d_in[1];
    const float* bias = (const float*)d_in[2];
    float* out        = (float*)d_out;

    causal_conv1d_kernel<<<NBLK, 256, 0, stream>>>(x, w, bias, out);
}